// Round 1
// 73.944 us; speedup vs baseline: 1.0174x; 1.0174x over previous
//
#include <hip/hip_runtime.h>
#include <math.h>

// B=16384, IN=64, HID=128, OUT=1, E=64, NMAP=1000 (fp32 in/out; bf16 MFMA inside)
//
// R7: single fused kernel, zero workspace use.
// Previous best (75 us) split routing + W1->bf16 frag prep (Ka) from compute
// (Kb) through a ~1.8 MB ws round-trip: two serialized launches, and Kb's
// prologue chased Ka's writes through poisoned / cross-XCD-incoherent L2
// (3-4 dependent HBM-latency hops before any MFMA).
// Here block (e,g) does everything locally:
//   - routes its own 1024 samples (4 KB coalesced num + c gathers; 64-way
//     redundant across experts but only ~4 MB aggregate, L2-resident)
//   - builds expert e's bf16 MFMA B-fragments in LDS straight from W1
//     (32 KB coalesced fp32 read; all 16 g-blocks of expert e share an XCD
//     under the default %8 mapping, so W1 HBM traffic stays ~2 MB)
//   - routing->compute dependency is a block-local __syncthreads, not a
//     kernel boundary.

#define B_N    16384
#define IN_D   64
#define HID_D  128
#define E_N    64
#define NGRP   16
#define GRP_S  (B_N / NGRP)     // 1024 samples routed per block
#define CAPC   256              // list capacity; observed data max ~192

typedef __attribute__((ext_vector_type(8))) short v8s;   // 8 bf16 (4 VGPRs)
typedef __attribute__((ext_vector_type(4))) float v4f;   // MFMA C/D

__device__ __forceinline__ short f2bf(float f) {         // fp32 -> bf16, RNE
    unsigned int u = __float_as_uint(f);
    u += 0x7fffu + ((u >> 16) & 1u);
    return (short)(u >> 16);
}

__global__ __launch_bounds__(256) void moe_fused(
    const float* __restrict__ x, const int* __restrict__ num,
    const int* __restrict__ c, const float* __restrict__ W1,
    const float* __restrict__ b1, const float* __restrict__ W2,
    const float* __restrict__ b2, float* __restrict__ out)
{
    __shared__ v8s   s_frag[IN_D * HID_D / 8];   // 16 KB bf16 W1 fragments
    __shared__ int   s_list[CAPC];
    __shared__ float s_yw[4][CAPC];
    __shared__ int   s_cnt;

    const int tid = threadIdx.x;
    const int e   = blockIdx.x & (E_N - 1);
    const int g   = blockIdx.x >> 6;

    // ---- issue all independent global loads first (overlap their latency) ----
    // my 4 routing samples (16 B coalesced)
    const int  s0 = g * GRP_S + tid * 4;
    const int4 nv = *(const int4*)&num[s0];

    // my slice of W1[e]: thread builds frags f0..f0+3 = 4 lanes of one
    // (w,nt,kh); frag f = ((w*2+nt)*2+kh)*64 + lane holds
    // B[n=16nt+(lane&15)][k=32kh+8q+j]  (layout identical to verified R6)
    const int f0    = tid * 4;
    const int w     = f0 >> 8, nt = (f0 >> 7) & 1, kh = (f0 >> 6) & 1;
    const int fq    = (f0 >> 4) & 3;
    const int hbase = 32 * w + 16 * nt + (f0 & 15);
    const float* W1e = W1 + (size_t)e * (IN_D * HID_D);
    float4 wv[8];
    #pragma unroll
    for (int j = 0; j < 8; ++j)
        wv[j] = *(const float4*)&W1e[(32 * kh + 8 * fq + j) * HID_D + hbase];

    if (tid == 0) s_cnt = 0;
    __syncthreads();

    // ---- route: expert-id gather, append matches to block-local list ----
    const int e0 = c[nv.x], e1 = c[nv.y], e2 = c[nv.z], e3 = c[nv.w];
    if (e0 == e) { int p = atomicAdd(&s_cnt, 1); if (p < CAPC) s_list[p] = s0;     }
    if (e1 == e) { int p = atomicAdd(&s_cnt, 1); if (p < CAPC) s_list[p] = s0 + 1; }
    if (e2 == e) { int p = atomicAdd(&s_cnt, 1); if (p < CAPC) s_list[p] = s0 + 2; }
    if (e3 == e) { int p = atomicAdd(&s_cnt, 1); if (p < CAPC) s_list[p] = s0 + 3; }

    // ---- convert W1 slice to bf16, drop into LDS fragment layout ----
    v8s t[4];
    #pragma unroll
    for (int j = 0; j < 8; ++j) {
        t[0][j] = f2bf(wv[j].x); t[1][j] = f2bf(wv[j].y);
        t[2][j] = f2bf(wv[j].z); t[3][j] = f2bf(wv[j].w);
    }
    #pragma unroll
    for (int i = 0; i < 4; ++i) s_frag[f0 + i] = t[i];

    // per-thread epilogue constants (independent loads, overlap with above)
    const int wave = __builtin_amdgcn_readfirstlane(tid >> 6);
    const int lane = tid & 63, l16 = lane & 15, qd = lane >> 4;
    const int h0   = 32 * wave + l16, h1 = h0 + 16;
    const float b1v0 = b1[e * HID_D + h0], b1v1 = b1[e * HID_D + h1];
    const float w2v0 = W2[e * HID_D + h0], w2v1 = W2[e * HID_D + h1];
    const float b2v  = b2[e];
    __syncthreads();

    // ---- B-fragments from LDS (contiguous b128 reads, conflict-free) ----
    v8s bfrag[2][2];
    #pragma unroll
    for (int n2 = 0; n2 < 2; ++n2)
        #pragma unroll
        for (int k2 = 0; k2 < 2; ++k2)
            bfrag[n2][k2] = s_frag[((wave * 2 + n2) * 2 + k2) * 64 + lane];

    const int total  = min(s_cnt, CAPC);
    const int ntiles = (total + 15) >> 4;
    for (int mt = 0; mt < ntiles; ++mt) {
        const int idx = mt * 16 + l16;
        const int s   = s_list[min(idx, total - 1)];
        const float4* row = (const float4*)(x + (size_t)s * IN_D);

        // A[m=l16][k=qd*8+j] (+32 second k-half)
        const float4 r0 = row[2 * qd],     r1 = row[2 * qd + 1];
        const float4 r2 = row[8 + 2 * qd], r3 = row[8 + 2 * qd + 1];
        v8s a0, a1;
        a0[0]=f2bf(r0.x); a0[1]=f2bf(r0.y); a0[2]=f2bf(r0.z); a0[3]=f2bf(r0.w);
        a0[4]=f2bf(r1.x); a0[5]=f2bf(r1.y); a0[6]=f2bf(r1.z); a0[7]=f2bf(r1.w);
        a1[0]=f2bf(r2.x); a1[1]=f2bf(r2.y); a1[2]=f2bf(r2.z); a1[3]=f2bf(r2.w);
        a1[4]=f2bf(r3.x); a1[5]=f2bf(r3.y); a1[6]=f2bf(r3.z); a1[7]=f2bf(r3.w);

        v4f acc0 = {0.f, 0.f, 0.f, 0.f};
        v4f acc1 = {0.f, 0.f, 0.f, 0.f};
        acc0 = __builtin_amdgcn_mfma_f32_16x16x32_bf16(a0, bfrag[0][0], acc0, 0, 0, 0);
        acc0 = __builtin_amdgcn_mfma_f32_16x16x32_bf16(a1, bfrag[0][1], acc0, 0, 0, 0);
        acc1 = __builtin_amdgcn_mfma_f32_16x16x32_bf16(a0, bfrag[1][0], acc1, 0, 0, 0);
        acc1 = __builtin_amdgcn_mfma_f32_16x16x32_bf16(a1, bfrag[1][1], acc1, 0, 0, 0);

        // C/D: col(h)=lane&15, row(sample)=qd*4+r. Fused bias/ReLU/W2 + h-reduce.
        #pragma unroll
        for (int r = 0; r < 4; ++r) {
            float v = fmaxf(acc0[r] + b1v0, 0.f) * w2v0
                    + fmaxf(acc1[r] + b1v1, 0.f) * w2v1;
            v += __shfl_xor(v, 1);
            v += __shfl_xor(v, 2);
            v += __shfl_xor(v, 4);
            v += __shfl_xor(v, 8);
            if (l16 == 0) s_yw[wave][mt * 16 + qd * 4 + r] = v;
        }
    }
    __syncthreads();

    for (int i = tid; i < total; i += 256) {
        const float tv = s_yw[0][i] + s_yw[1][i] + s_yw[2][i] + s_yw[3][i] + b2v;
        out[s_list[i]] = 1.0f / (1.0f + expf(-tv));
    }
}

extern "C" void kernel_launch(void* const* d_in, const int* in_sizes, int n_in,
                              void* d_out, int out_size, void* d_ws, size_t ws_size,
                              hipStream_t stream)
{
    const float* x   = (const float*)d_in[0];
    const int*   num = (const int*)  d_in[1];
    const int*   c   = (const int*)  d_in[2];
    const float* W1  = (const float*)d_in[3];
    const float* b1  = (const float*)d_in[4];
    const float* W2  = (const float*)d_in[5];
    const float* b2  = (const float*)d_in[6];
    float*       out = (float*)d_out;
    (void)d_ws; (void)ws_size;

    moe_fused<<<dim3(E_N * NGRP), dim3(256), 0, stream>>>(x, num, c, W1, b1, W2, b2, out);
}

// Round 2
// 72.865 us; speedup vs baseline: 1.0325x; 1.0148x over previous
//
#include <hip/hip_runtime.h>
#include <math.h>

// B=16384, IN=64, HID=128, OUT=1, E=64, NMAP=1000 (fp32 in/out; bf16 MFMA inside)
//
// R8: fused kernel (R7 structure) + wave-aggregated routing append.
// R7's routing did up to 1024 serialized same-address LDS atomicAdds per
// block (256 thr x 4 samples on one counter) = ~1024 cyc/block of serial
// time on the pre-sync critical path. Replaced with per-slot __ballot +
// one atomicAdd per wave + popc-prefix placement: 16 atomics/block max.
// Everything else identical to the verified R7 kernel.

#define B_N    16384
#define IN_D   64
#define HID_D  128
#define E_N    64
#define NGRP   16
#define GRP_S  (B_N / NGRP)     // 1024 samples routed per block
#define CAPC   256              // list capacity; observed per-block max ~55

typedef __attribute__((ext_vector_type(8))) short v8s;   // 8 bf16 (4 VGPRs)
typedef __attribute__((ext_vector_type(4))) float v4f;   // MFMA C/D

__device__ __forceinline__ short f2bf(float f) {         // fp32 -> bf16, RNE
    unsigned int u = __float_as_uint(f);
    u += 0x7fffu + ((u >> 16) & 1u);
    return (short)(u >> 16);
}

__global__ __launch_bounds__(256) void moe_fused(
    const float* __restrict__ x, const int* __restrict__ num,
    const int* __restrict__ c, const float* __restrict__ W1,
    const float* __restrict__ b1, const float* __restrict__ W2,
    const float* __restrict__ b2, float* __restrict__ out)
{
    __shared__ v8s   s_frag[IN_D * HID_D / 8];   // 16 KB bf16 W1 fragments
    __shared__ int   s_list[CAPC];
    __shared__ float s_yw[4][CAPC];
    __shared__ int   s_cnt;

    const int tid = threadIdx.x;
    const int e   = blockIdx.x & (E_N - 1);
    const int g   = blockIdx.x >> 6;

    // ---- issue all independent global loads first (overlap their latency) ----
    // my 4 routing samples (16 B coalesced)
    const int  s0 = g * GRP_S + tid * 4;
    const int4 nv = *(const int4*)&num[s0];

    // my slice of W1[e]: thread builds frags f0..f0+3 = 4 lanes of one
    // (w,nt,kh); frag f = ((w*2+nt)*2+kh)*64 + lane holds
    // B[n=16nt+(lane&15)][k=32kh+8q+j]  (layout identical to verified R6/R7)
    const int f0    = tid * 4;
    const int w     = f0 >> 8, nt = (f0 >> 7) & 1, kh = (f0 >> 6) & 1;
    const int fq    = (f0 >> 4) & 3;
    const int hbase = 32 * w + 16 * nt + (f0 & 15);
    const float* W1e = W1 + (size_t)e * (IN_D * HID_D);
    float4 wv[8];
    #pragma unroll
    for (int j = 0; j < 8; ++j)
        wv[j] = *(const float4*)&W1e[(32 * kh + 8 * fq + j) * HID_D + hbase];

    if (tid == 0) s_cnt = 0;
    __syncthreads();

    // ---- route: expert-id gather, wave-aggregated append (16 atomics/blk) ----
    const int lane = tid & 63;
    const int wave = __builtin_amdgcn_readfirstlane(tid >> 6);
    const unsigned long long lmask = (1ull << lane) - 1ull;
    const int es[4] = { c[nv.x], c[nv.y], c[nv.z], c[nv.w] };
    #pragma unroll
    for (int i = 0; i < 4; ++i) {
        const bool hit = (es[i] == e);
        const unsigned long long m = __ballot(hit);
        int base = 0;
        if (lane == 0) base = atomicAdd(&s_cnt, __popcll(m));
        base = __shfl(base, 0);
        if (hit) {
            const int p = base + __popcll(m & lmask);
            if (p < CAPC) s_list[p] = s0 + i;
        }
    }

    // ---- convert W1 slice to bf16, drop into LDS fragment layout ----
    v8s t[4];
    #pragma unroll
    for (int j = 0; j < 8; ++j) {
        t[0][j] = f2bf(wv[j].x); t[1][j] = f2bf(wv[j].y);
        t[2][j] = f2bf(wv[j].z); t[3][j] = f2bf(wv[j].w);
    }
    #pragma unroll
    for (int i = 0; i < 4; ++i) s_frag[f0 + i] = t[i];

    // per-thread epilogue constants (independent loads, overlap with above)
    const int l16 = lane & 15, qd = lane >> 4;
    const int h0  = 32 * wave + l16, h1 = h0 + 16;
    const float b1v0 = b1[e * HID_D + h0], b1v1 = b1[e * HID_D + h1];
    const float w2v0 = W2[e * HID_D + h0], w2v1 = W2[e * HID_D + h1];
    const float b2v  = b2[e];
    __syncthreads();

    // ---- B-fragments from LDS (contiguous b128 reads, conflict-free) ----
    v8s bfrag[2][2];
    #pragma unroll
    for (int n2 = 0; n2 < 2; ++n2)
        #pragma unroll
        for (int k2 = 0; k2 < 2; ++k2)
            bfrag[n2][k2] = s_frag[((wave * 2 + n2) * 2 + k2) * 64 + lane];

    const int total  = min(s_cnt, CAPC);
    const int ntiles = (total + 15) >> 4;
    for (int mt = 0; mt < ntiles; ++mt) {
        const int idx = mt * 16 + l16;
        const int s   = s_list[min(idx, total - 1)];
        const float4* row = (const float4*)(x + (size_t)s * IN_D);

        // A[m=l16][k=qd*8+j] (+32 second k-half)
        const float4 r0 = row[2 * qd],     r1 = row[2 * qd + 1];
        const float4 r2 = row[8 + 2 * qd], r3 = row[8 + 2 * qd + 1];
        v8s a0, a1;
        a0[0]=f2bf(r0.x); a0[1]=f2bf(r0.y); a0[2]=f2bf(r0.z); a0[3]=f2bf(r0.w);
        a0[4]=f2bf(r1.x); a0[5]=f2bf(r1.y); a0[6]=f2bf(r1.z); a0[7]=f2bf(r1.w);
        a1[0]=f2bf(r2.x); a1[1]=f2bf(r2.y); a1[2]=f2bf(r2.z); a1[3]=f2bf(r2.w);
        a1[4]=f2bf(r3.x); a1[5]=f2bf(r3.y); a1[6]=f2bf(r3.z); a1[7]=f2bf(r3.w);

        v4f acc0 = {0.f, 0.f, 0.f, 0.f};
        v4f acc1 = {0.f, 0.f, 0.f, 0.f};
        acc0 = __builtin_amdgcn_mfma_f32_16x16x32_bf16(a0, bfrag[0][0], acc0, 0, 0, 0);
        acc0 = __builtin_amdgcn_mfma_f32_16x16x32_bf16(a1, bfrag[0][1], acc0, 0, 0, 0);
        acc1 = __builtin_amdgcn_mfma_f32_16x16x32_bf16(a0, bfrag[1][0], acc1, 0, 0, 0);
        acc1 = __builtin_amdgcn_mfma_f32_16x16x32_bf16(a1, bfrag[1][1], acc1, 0, 0, 0);

        // C/D: col(h)=lane&15, row(sample)=qd*4+r. Fused bias/ReLU/W2 + h-reduce.
        #pragma unroll
        for (int r = 0; r < 4; ++r) {
            float v = fmaxf(acc0[r] + b1v0, 0.f) * w2v0
                    + fmaxf(acc1[r] + b1v1, 0.f) * w2v1;
            v += __shfl_xor(v, 1);
            v += __shfl_xor(v, 2);
            v += __shfl_xor(v, 4);
            v += __shfl_xor(v, 8);
            if (l16 == 0) s_yw[wave][mt * 16 + qd * 4 + r] = v;
        }
    }
    __syncthreads();

    for (int i = tid; i < total; i += 256) {
        const float tv = s_yw[0][i] + s_yw[1][i] + s_yw[2][i] + s_yw[3][i] + b2v;
        out[s_list[i]] = 1.0f / (1.0f + expf(-tv));
    }
}

extern "C" void kernel_launch(void* const* d_in, const int* in_sizes, int n_in,
                              void* d_out, int out_size, void* d_ws, size_t ws_size,
                              hipStream_t stream)
{
    const float* x   = (const float*)d_in[0];
    const int*   num = (const int*)  d_in[1];
    const int*   c   = (const int*)  d_in[2];
    const float* W1  = (const float*)d_in[3];
    const float* b1  = (const float*)d_in[4];
    const float* W2  = (const float*)d_in[5];
    const float* b2  = (const float*)d_in[6];
    float*       out = (float*)d_out;
    (void)d_ws; (void)ws_size;

    moe_fused<<<dim3(E_N * NGRP), dim3(256), 0, stream>>>(x, num, c, W1, b1, W2, b2, out);
}